// Round 2
// baseline (162.790 us; speedup 1.0000x reference)
//
#include <hip/hip_runtime.h>
#include <hip/hip_bf16.h>

// Problem: x[32,64,224,224] f32 -> BN(inference affine)+ReLU -> 1x1 conv (64->32)
//          -> 2x2 avgpool s2 -> out[32,32,112,112] f32.
// Algebra: conv (linear over C) commutes with avgpool (linear over space),
//          so: relu-affine -> pool 2x2 -> 32x64 matvec. ReLU must stay before pool.
// Streaming: each x element used exactly once -> memory-bound. Floor ~66-73us
//   (463 MB at the ~7 TB/s fillBuffer-observed stream rate).
// R2 change: 2 adjacent pooled pixels per thread -> float4 (16B/lane) loads,
//   float2 stores. 16B/lane is the coalescing sweet spot (guide §2).

#define EPS_BN 1e-5f

constexpr int N_   = 32;
constexpr int CIN  = 64;
constexpr int COUT = 32;
constexpr int H_   = 224;
constexpr int W_   = 224;
constexpr int H2   = 112;
constexpr int W2   = 112;
constexpr int PIX  = N_ * H2 * W2;       // 401408 pooled pixels
constexpr int BLK  = 256;
constexpr int PAIRS = PIX / 2;           // 200704 pixel-pairs, one per thread

// d_ws layout (floats): [0..63]=scale, [64..127]=bias, [128..128+2048)=wT[c][o]
__global__ void prep_kernel(const float* __restrict__ conv_w,
                            const float* __restrict__ gamma,
                            const float* __restrict__ beta,
                            const float* __restrict__ rmean,
                            const float* __restrict__ rvar,
                            float* __restrict__ ws) {
    int c = threadIdx.x;            // 64 threads, one per input channel
    if (c < CIN) {
        float s = gamma[c] * rsqrtf(rvar[c] + EPS_BN);
        float b = beta[c] - rmean[c] * s;
        ws[c]        = s;
        ws[CIN + c]  = b;
        // transpose conv_w [o][c] -> wT [c][o] so per-c weight rows are contiguous
        for (int o = 0; o < COUT; ++o)
            ws[2 * CIN + c * COUT + o] = conv_w[o * CIN + c];
    }
}

__global__ __launch_bounds__(BLK) void fused_kernel(const float* __restrict__ x,
                                                    const float* __restrict__ ws,
                                                    float* __restrict__ out) {
    const float* __restrict__ sc = ws;            // [64]
    const float* __restrict__ bi = ws + CIN;      // [64]
    const float* __restrict__ wT = ws + 2 * CIN;  // [64][32]

    int j = blockIdx.x * BLK + threadIdx.x;       // pair id, PAIRS % BLK == 0
    int n  = j / (H2 * W2 / 2);
    int r  = j - n * (H2 * W2 / 2);
    int h2 = r / (W2 / 2);
    int w4 = r - h2 * (W2 / 2);                   // pair index; pooled cols 2*w4, 2*w4+1

    // base of the 2x4 window (2 rows x 4 cols of x) for channel 0; 16B-aligned
    const float* __restrict__ px =
        x + ((size_t)n * CIN * H_ + (size_t)(2 * h2)) * W_ + (size_t)(4 * w4);

    float acc0[COUT], acc1[COUT];
#pragma unroll
    for (int o = 0; o < COUT; ++o) { acc0[o] = 0.0f; acc1[o] = 0.0f; }

#pragma unroll
    for (int c = 0; c < CIN; ++c) {
        const float* p = px + (size_t)c * (H_ * W_);
        float4 r0 = *reinterpret_cast<const float4*>(p);
        float4 r1 = *reinterpret_cast<const float4*>(p + W_);
        float s = sc[c];   // uniform address -> s_load, broadcast
        float b = bi[c];
        float y0 = fmaxf(fmaf(r0.x, s, b), 0.0f)
                 + fmaxf(fmaf(r0.y, s, b), 0.0f)
                 + fmaxf(fmaf(r1.x, s, b), 0.0f)
                 + fmaxf(fmaf(r1.y, s, b), 0.0f);
        float y1 = fmaxf(fmaf(r0.z, s, b), 0.0f)
                 + fmaxf(fmaf(r0.w, s, b), 0.0f)
                 + fmaxf(fmaf(r1.z, s, b), 0.0f)
                 + fmaxf(fmaf(r1.w, s, b), 0.0f);
        y0 *= 0.25f;       // 2x2 mean
        y1 *= 0.25f;
#pragma unroll
        for (int o = 0; o < COUT; ++o) {
            float w = wT[c * COUT + o];           // uniform -> SGPR operand
            acc0[o] = fmaf(w, y0, acc0[o]);
            acc1[o] = fmaf(w, y1, acc1[o]);
        }
    }

    // out[((n*COUT + o)*H2 + h2)*W2 + 2*w4], pairs contiguous -> float2 store
    float* __restrict__ po =
        out + ((size_t)n * COUT * H2 + (size_t)h2) * W2 + (size_t)(2 * w4);
#pragma unroll
    for (int o = 0; o < COUT; ++o) {
        float2 v = make_float2(acc0[o], acc1[o]);
        *reinterpret_cast<float2*>(po + (size_t)o * (H2 * W2)) = v;
    }
}

extern "C" void kernel_launch(void* const* d_in, const int* in_sizes, int n_in,
                              void* d_out, int out_size, void* d_ws, size_t ws_size,
                              hipStream_t stream) {
    const float* x      = (const float*)d_in[0];
    const float* conv_w = (const float*)d_in[1];
    const float* gamma  = (const float*)d_in[2];
    const float* beta   = (const float*)d_in[3];
    const float* rmean  = (const float*)d_in[4];
    const float* rvar   = (const float*)d_in[5];
    float* out = (float*)d_out;
    float* ws  = (float*)d_ws;

    prep_kernel<<<1, 64, 0, stream>>>(conv_w, gamma, beta, rmean, rvar, ws);
    fused_kernel<<<PAIRS / BLK, BLK, 0, stream>>>(x, ws, out);
}

// Round 3
// 141.915 us; speedup vs baseline: 1.1471x; 1.1471x over previous
//
#include <hip/hip_runtime.h>

// x[32,64,224,224] f32 -> BN(affine)+ReLU -> 1x1 conv(64->32) -> avgpool 2x2 s2
//   == (per pixel-pair algebra) relu-affine -> pool -> 32x64 matvec.
// Streaming, zero reuse of x -> memory-bound. Floor: 411MB read + 51MB write
//   at ~6.3 TB/s ~= 73.5us.
// R3 structure: persistent blocks (1/CU), double-buffered LDS staging via
//   global_load_lds (zero VGPR cost, 56KB in flight/CU), counted vmcnt(7)
//   so prefetch survives barriers (never __syncthreads in the main loop).

#define EPS_BN 1e-5f

constexpr int N_   = 32;
constexpr int CIN  = 64;
constexpr int COUT = 32;
constexpr int H_   = 224;
constexpr int W_   = 224;
constexpr int H2   = 112;
constexpr int W2   = 112;

constexpr int NROWS   = N_ * H2;        // 3584 (n,h2) row tasks
constexpr int BLOCKS  = 256;            // 1 per CU (LDS-bound)
constexpr int THREADS = 512;            // 8 waves
constexpr int ROWS_PB = NROWS / BLOCKS; // 14 rows per block
constexpr int FILLS   = 2 * ROWS_PB;    // 28 fills (2 channel-halves per row)
constexpr int CHH     = 32;             // channels per fill
constexpr int STRIP_F4 = (2 * W_) / 4;  // 112 float4 chunks per channel strip
constexpr int FILL_F4  = CHH * STRIP_F4;// 3584 chunks per fill
constexpr int LPT      = FILL_F4 / THREADS; // 7 global_load_lds per thread
constexpr int BUF_FLOATS = CHH * 2 * W_;    // 14336 floats = 57344 B per buffer

__global__ __launch_bounds__(THREADS) void fused(
    const float* __restrict__ x,
    const float* __restrict__ conv_w,
    const float* __restrict__ gamma,
    const float* __restrict__ beta,
    const float* __restrict__ rmean,
    const float* __restrict__ rvar,
    float* __restrict__ out) {
  __shared__ float xb[2][BUF_FLOATS];   // 2 x 57344 B staged x strips
  __shared__ float sb[2][CIN];          // folded BN scale/bias (x0.25 pool)

  const int tid = threadIdx.x;

  // One-time: folded scale/bias. 0.25*relu(s*x+b) == relu(0.25s*x + 0.25b).
  if (tid < CIN) {
    float s = gamma[tid] * rsqrtf(rvar[tid] + EPS_BN);
    float b = beta[tid] - rmean[tid] * s;
    sb[0][tid] = 0.25f * s;
    sb[1][tid] = 0.25f * b;
  }
  __syncthreads();   // full drain once, before the counted-vmcnt pipeline

  const int p  = tid & 127;                                   // pixel 0..127 (<112 active)
  const int ru = __builtin_amdgcn_readfirstlane(tid >> 7);    // role 0..3 -> outputs 8ru..8ru+7
  const bool act = p < W2;

  // Stage fill f (32 channel strips of one (n,h2) row-pair) into xb[buf].
  // LDS dest is linear j*16B (wave-uniform base + lane*16 as required);
  // global src is per-lane (strip-crossing lanes are fine).
  auto STAGE = [&](int buf, int f) {
    const int g  = blockIdx.x * ROWS_PB + (f >> 1);
    const int n  = g / H2;
    const int h2 = g - n * H2;
    const int c0 = (f & 1) * CHH;
    const float* base = x + ((size_t)(n * CIN + c0) * H_ + 2 * h2) * W_;
    float* dst = &xb[buf][0];
#pragma unroll
    for (int k = 0; k < LPT; ++k) {
      int j  = k * THREADS + tid;
      int c  = j / STRIP_F4;            // 0..31
      int wi = j - c * STRIP_F4;        // 0..111 (float4 index within strip)
      const float* src = base + (size_t)c * (H_ * W_) + wi * 4;
      __builtin_amdgcn_global_load_lds(
          (const __attribute__((address_space(1))) void*)src,
          (__attribute__((address_space(3))) void*)(dst + j * 4),
          16, 0, 0);
    }
  };

  float acc[8];

  STAGE(0, 0);
  for (int f = 0; f < FILLS; ++f) {
    const int cur = f & 1;

    if (f + 1 < FILLS) {
      STAGE(cur ^ 1, f + 1);
      // Drain everything except the LPT loads just issued -> xb[cur] ready,
      // xb[cur^1] prefetch stays in flight across the barrier.
      asm volatile("s_waitcnt vmcnt(%0)" :: "n"(LPT) : "memory");
    } else {
      asm volatile("s_waitcnt vmcnt(0)" ::: "memory");
    }
    __builtin_amdgcn_s_barrier();
    __builtin_amdgcn_sched_barrier(0);

    const int g  = blockIdx.x * ROWS_PB + (f >> 1);
    const int n  = g / H2;
    const int h2 = g - n * H2;
    const int c0 = cur * CHH;           // fills alternate channel halves

    if (cur == 0) {
#pragma unroll
      for (int o = 0; o < 8; ++o) acc[o] = 0.0f;
    }
    if (act) {
      const float* cb = &xb[cur][0];
#pragma unroll
      for (int c = 0; c < CHH; ++c) {
        float s  = sb[0][c0 + c];       // uniform addr -> LDS broadcast
        float bb = sb[1][c0 + c];
        float2 u = *reinterpret_cast<const float2*>(cb + c * (2 * W_) + 2 * p);
        float2 v = *reinterpret_cast<const float2*>(cb + c * (2 * W_) + W_ + 2 * p);
        float y = fmaxf(fmaf(u.x, s, bb), 0.0f) + fmaxf(fmaf(u.y, s, bb), 0.0f)
                + fmaxf(fmaf(v.x, s, bb), 0.0f) + fmaxf(fmaf(v.y, s, bb), 0.0f);
#pragma unroll
        for (int o = 0; o < 8; ++o)     // conv_w idx wave-uniform -> s_load
          acc[o] = fmaf(conv_w[(ru * 8 + o) * CIN + c0 + c], y, acc[o]);
      }
      if (cur == 1) {                   // row complete -> store 8 outputs
        size_t ob = ((size_t)(n * COUT + ru * 8) * H2 + h2) * W2 + p;
#pragma unroll
        for (int o = 0; o < 8; ++o)
          out[ob + (size_t)o * (H2 * W2)] = acc[o];
      }
    }

    __builtin_amdgcn_sched_barrier(0);
    __builtin_amdgcn_s_barrier();       // xb[cur] free for restage next iter
  }
}

extern "C" void kernel_launch(void* const* d_in, const int* in_sizes, int n_in,
                              void* d_out, int out_size, void* d_ws, size_t ws_size,
                              hipStream_t stream) {
  const float* x      = (const float*)d_in[0];
  const float* conv_w = (const float*)d_in[1];
  const float* gamma  = (const float*)d_in[2];
  const float* beta   = (const float*)d_in[3];
  const float* rmean  = (const float*)d_in[4];
  const float* rvar   = (const float*)d_in[5];
  float* out = (float*)d_out;

  fused<<<BLOCKS, THREADS, 0, stream>>>(x, conv_w, gamma, beta, rmean, rvar, out);
}

// Round 4
// 138.513 us; speedup vs baseline: 1.1753x; 1.0246x over previous
//
#include <hip/hip_runtime.h>

// x[32,64,224,224] f32 -> BN(affine)+ReLU -> 1x1 conv(64->32) -> avgpool 2x2 s2
//   == relu-affine -> pool -> 32x64 matvec (conv commutes with pool).
// Memory-bound streaming: 411MB read + 51MB write ~= 73.5us at 6.3 TB/s.
// R4: R3's zero-VGPR global_load_lds pipeline, fixed for parallelism:
//   - 512 blocks (2/CU) so blocks desynchronize and cover each other's stalls
//   - 448 threads = 112 pixels x 4 roles (no idle lanes), LPT = 4 exactly
//   - 28KB fills, stage issued at END of iter -> full-iteration overlap window
//   - conv_w in LDS (role not wave-uniform; <=2 addrs/wave = free broadcast)

#define EPS_BN 1e-5f

constexpr int N_   = 32;
constexpr int CIN  = 64;
constexpr int COUT = 32;
constexpr int H_   = 224;
constexpr int W_   = 224;
constexpr int H2   = 112;
constexpr int W2   = 112;

constexpr int BLOCKS  = 512;               // 2 per CU
constexpr int THREADS = 448;               // 7 waves; 4 roles x 112 pixels
constexpr int ROWS_PB = (N_ * H2) / BLOCKS;    // 7 (n,h2) rows per block
constexpr int CHH     = 16;                // channels per fill
constexpr int FPR     = CIN / CHH;         // 4 fills per row
constexpr int FILLS   = ROWS_PB * FPR;     // 28
constexpr int STRIP_F4 = (2 * W_) / 4;     // 112 float4 chunks per channel strip
constexpr int FILL_F4  = CHH * STRIP_F4;   // 1792
constexpr int LPT      = FILL_F4 / THREADS;    // 4 global_load_lds per thread
constexpr int BUF_FLOATS = CHH * 2 * W_;       // 7168 floats = 28672 B

__global__ __launch_bounds__(THREADS) void fused(
    const float* __restrict__ x,
    const float* __restrict__ conv_w,
    const float* __restrict__ gamma,
    const float* __restrict__ beta,
    const float* __restrict__ rmean,
    const float* __restrict__ rvar,
    float* __restrict__ out) {
  __shared__ float xb[2][BUF_FLOATS];      // 2 x 28672 B staged x strips
  __shared__ float wt[CIN * COUT];         // conv_w transposed to [c][o]
  __shared__ float sb[2][CIN];             // folded BN scale/bias (x0.25 pool)

  const int tid = threadIdx.x;

  // Prologue (drained by __syncthreads before the counted-vmcnt pipeline).
  for (int j = tid; j < CIN * COUT; j += THREADS) {
    int c = j >> 5, o = j & 31;            // wt[c*32+o] = conv_w[o*64+c]
    wt[j] = conv_w[o * CIN + c];
  }
  if (tid < CIN) {
    float s = gamma[tid] * rsqrtf(rvar[tid] + EPS_BN);
    float b = beta[tid] - rmean[tid] * s;
    sb[0][tid] = 0.25f * s;                // 0.25*relu(s*x+b) == relu(.25s*x+.25b)
    sb[1][tid] = 0.25f * b;
  }
  __syncthreads();

  const int p  = tid % W2;                 // pixel 0..111 (all threads active)
  const int ro = tid / W2;                 // role 0..3 -> outputs 8ro..8ro+7

  // Stage fill f (16 channel strips of one (n,h2) row-pair) into xb[buf].
  // LDS dest linear in j (wave-uniform base + lane*16B); global src per-lane.
  auto STAGE = [&](int buf, int f) {
    const int g  = blockIdx.x * ROWS_PB + f / FPR;
    const int n  = g / H2;
    const int h2 = g - n * H2;
    const int c0 = (f & (FPR - 1)) * CHH;
    const float* base = x + ((size_t)(n * CIN + c0) * H_ + 2 * h2) * W_;
    float* dst = &xb[buf][0];
#pragma unroll
    for (int k = 0; k < LPT; ++k) {
      int j  = k * THREADS + tid;          // 0..1791
      int c  = j / STRIP_F4;               // 0..15
      int wi = j - c * STRIP_F4;           // 0..111
      const float* src = base + (size_t)c * (H_ * W_) + wi * 4;
      __builtin_amdgcn_global_load_lds(
          (const __attribute__((address_space(1))) void*)src,
          (__attribute__((address_space(3))) void*)(dst + j * 4),
          16, 0, 0);
    }
  };

  float acc[8];

  STAGE(0, 0);
  STAGE(1, 1);
#pragma unroll 1
  for (int f = 0; f < FILLS; ++f) {
    // Wait fill f complete; fill f+1 (and older stores) may stay in flight.
    // vmcnt(LPT): <=LPT outstanding guarantees everything older than the
    // newest LPT loads (i.e. fill f, plus any stores) has retired.
    if (f + 1 < FILLS) {
      asm volatile("s_waitcnt vmcnt(%0)" :: "n"(LPT) : "memory");
    } else {
      asm volatile("s_waitcnt vmcnt(0)" ::: "memory");
    }
    __builtin_amdgcn_s_barrier();
    __builtin_amdgcn_sched_barrier(0);

    const int sub = f & (FPR - 1);
    const int c0  = sub * CHH;
    if (sub == 0) {
#pragma unroll
      for (int o = 0; o < 8; ++o) acc[o] = 0.0f;
    }

    const float* cb = &xb[f & 1][0];
#pragma unroll
    for (int c = 0; c < CHH; ++c) {
      float s  = sb[0][c0 + c];
      float bb = sb[1][c0 + c];
      float2 u = *reinterpret_cast<const float2*>(cb + c * (2 * W_) + 2 * p);
      float2 v = *reinterpret_cast<const float2*>(cb + c * (2 * W_) + W_ + 2 * p);
      float y = fmaxf(fmaf(u.x, s, bb), 0.0f) + fmaxf(fmaf(u.y, s, bb), 0.0f)
              + fmaxf(fmaf(v.x, s, bb), 0.0f) + fmaxf(fmaf(v.y, s, bb), 0.0f);
      const float* wrow = wt + (c0 + c) * COUT + ro * 8;  // <=2 addrs/wave: free
#pragma unroll
      for (int o = 0; o < 8; ++o)
        acc[o] = fmaf(wrow[o], y, acc[o]);
    }

    if (sub == FPR - 1) {                  // row complete -> store 8 outputs
      const int g  = blockIdx.x * ROWS_PB + f / FPR;
      const int n  = g / H2;
      const int h2 = g - n * H2;
      size_t ob = ((size_t)(n * COUT + ro * 8) * H2 + h2) * W2 + p;
#pragma unroll
      for (int o = 0; o < 8; ++o)
        out[ob + (size_t)o * (H2 * W2)] = acc[o];
    }

    __builtin_amdgcn_sched_barrier(0);
    __builtin_amdgcn_s_barrier();          // xb[f&1] now free for restage
    __builtin_amdgcn_sched_barrier(0);
    if (f + 2 < FILLS) STAGE(f & 1, f + 2);
  }
}

extern "C" void kernel_launch(void* const* d_in, const int* in_sizes, int n_in,
                              void* d_out, int out_size, void* d_ws, size_t ws_size,
                              hipStream_t stream) {
  const float* x      = (const float*)d_in[0];
  const float* conv_w = (const float*)d_in[1];
  const float* gamma  = (const float*)d_in[2];
  const float* beta   = (const float*)d_in[3];
  const float* rmean  = (const float*)d_in[4];
  const float* rvar   = (const float*)d_in[5];
  float* out = (float*)d_out;

  fused<<<BLOCKS, THREADS, 0, stream>>>(x, conv_w, gamma, beta, rmean, rvar, out);
}